// Round 10
// baseline (527.095 us; speedup 1.0000x reference)
//
#include <hip/hip_runtime.h>
#include <math.h>

// ---------------------------------------------------------------------------
// ImprovedCrossBorderGNN: 3-layer edge-conditioned GAT, N=50000, E=1.6M, H=128
// CSR (dst-grouped) built once; per layer: bf16 MFMA GEMM g=h@W (fused
// a_src/a_dst epilogue), then softmax-stats pass + L2-resident sliced gather.
// R1: mean() via two-stage reduction. R2: bf16 g; parallel scans.
// R4: CSR via two-level counting sort. R5: register-blocked GEMM.
// R6/R7: wide pipelined gather -> hit ~3.3TB/s L3 service ceiling (12.8MB
//        table uniformly gathered by all 8 XCDs; 4MB L2 each -> 59% hit).
// R8: MFMA bf16 GEMM; 4B/edge/layer records; bf16 hidden states.
// R9: serial-chain fusion (A = count||encoder||wpack, B = place||gemm1).
// R10: agg split into k_soft (online softmax stats m,1/s per node) and
//      k_gath (4 channel-slices of 32ch; slice = blockIdx&3 so each XCD's
//      L2 caches one 3.2MB slice -> gather L2-resident; no wred in gather).
// ---------------------------------------------------------------------------

#define H 128
#define NF 8
#define EPB 4096  // edges per block in count/place (256 threads x 16)

typedef __attribute__((ext_vector_type(8))) short short8v;
typedef __attribute__((ext_vector_type(4))) float f32x4;

__device__ __forceinline__ float wred_sum(float x) {
#pragma unroll
    for (int m = 32; m >= 1; m >>= 1) x += __shfl_xor(x, m, 64);
    return x;
}
__device__ __forceinline__ float wred_max(float x) {
#pragma unroll
    for (int m = 32; m >= 1; m >>= 1) x = fmaxf(x, __shfl_xor(x, m, 64));
    return x;
}
__device__ __forceinline__ ushort f2bf(float f) {
    uint u = __float_as_uint(f);
    uint r = (u + 0x7FFFu + ((u >> 16) & 1u)) >> 16;  // round-to-nearest-even
    return (ushort)r;
}
__device__ __forceinline__ float bflo(uint q) { return __uint_as_float(q << 16); }
__device__ __forceinline__ float bfhi(uint q) { return __uint_as_float(q & 0xffff0000u); }

// ---- Kernel A: count || encoder || wpack (independent roles) ---------------
__global__ void k_fusedA(const int* __restrict__ ei, const float* __restrict__ ea,
                         int E, int nblk, int nbuckets, int* __restrict__ bucketTotal,
                         int* __restrict__ blockBase, float2* __restrict__ pmean,
                         const float* __restrict__ x, const float* __restrict__ encW,
                         const float* __restrict__ encb, const float* __restrict__ bng,
                         const float* __restrict__ bnb, float* __restrict__ h0,
                         ushort* __restrict__ hb, int N, int GB8,
                         const float* __restrict__ W1, const float* __restrict__ W2,
                         const float* __restrict__ W3, ushort* __restrict__ Wp) {
    __shared__ int hist[256];
    __shared__ float sx[4], sy[4];
    __shared__ float xs[8 * NF];
    const int bx = blockIdx.x;
    const int t = threadIdx.x;  // 256

    if (bx < nblk) {
        int blk = bx;
        hist[t] = 0;
        __syncthreads();
        int base = blk * EPB;
        float px = 0.f, py = 0.f;
#pragma unroll
        for (int i = 0; i < 16; ++i) {
            int e = base + i * 256 + t;
            if (e < E) {
                int d = ei[E + e];
                atomicAdd(&hist[d >> 8], 1);
                const float2 z = *(const float2*)(ea + 2 * (size_t)e);
                px += z.x; py += z.y;
            }
        }
        px = wred_sum(px); py = wred_sum(py);
        if ((t & 63) == 0) { sx[t >> 6] = px; sy[t >> 6] = py; }
        __syncthreads();
        if (t == 0) {
            pmean[blk] = make_float2(sx[0] + sx[1] + sx[2] + sx[3],
                                     sy[0] + sy[1] + sy[2] + sy[3]);
        }
        if (t < nbuckets) {
            int c = hist[t];
            int old = (c > 0) ? atomicAdd(&bucketTotal[t], c) : 0;
            blockBase[t * nblk + blk] = old;
        }
    } else if (bx < nblk + GB8) {
        int nb = (bx - nblk) * 8;
        if (t < 64) {
            size_t idx = (size_t)nb * NF + t;
            xs[t] = (idx < (size_t)N * NF) ? x[idx] : 0.f;
        }
        __syncthreads();
        int jt = t & 31, i = t >> 5;
        int node = nb + i;
        int j4 = jt * 4;
        float ax = 0.f, ay = 0.f, az = 0.f, aw = 0.f;
#pragma unroll
        for (int k = 0; k < NF; ++k) {
            float hx = xs[i * NF + k];
            const float4 w = *(const float4*)(encW + k * H + j4);
            ax = fmaf(hx, w.x, ax); ay = fmaf(hx, w.y, ay);
            az = fmaf(hx, w.z, az); aw = fmaf(hx, w.w, aw);
        }
        if (node < N) {
            const float inv = 0.9999950000374997f;  // 1/sqrt(1+1e-5)
            const float4 eb = *(const float4*)(encb + j4);
            const float4 gg = *(const float4*)(bng + j4);
            const float4 bb = *(const float4*)(bnb + j4);
            float4 o;
            o.x = fmaxf(0.f, (ax + eb.x) * (gg.x * inv) + bb.x);
            o.y = fmaxf(0.f, (ay + eb.y) * (gg.y * inv) + bb.y);
            o.z = fmaxf(0.f, (az + eb.z) * (gg.z * inv) + bb.z);
            o.w = fmaxf(0.f, (aw + eb.w) * (gg.w * inv) + bb.w);
            *(float4*)(h0 + (size_t)node * H + j4) = o;
            uint2 ob;
            ob.x = (uint)f2bf(o.x) | ((uint)f2bf(o.y) << 16);
            ob.y = (uint)f2bf(o.z) | ((uint)f2bf(o.w) << 16);
            *(uint2*)(hb + (size_t)node * H + j4) = ob;
        }
    } else {
        int layer = bx - nblk - GB8;
        const float* W = (layer == 0) ? W1 : ((layer == 1) ? W2 : W3);
        for (int idx = t; idx < 16384; idx += 256) {
            int i = idx & 7;
            int lane = (idx >> 3) & 63;
            int ft = idx >> 9;
            int kt = ft & 3, nt = ft >> 2;
            int k = kt * 32 + (lane >> 4) * 8 + i;
            int n = nt * 16 + (lane & 15);
            Wp[layer * 16384 + idx] = f2bf(W[k * H + n]);
        }
    }
}

// ---- scan + park (1 block) -------------------------------------------------
__global__ void k_scan_park(const int* __restrict__ bucketTotal, int nbuckets,
                            int* __restrict__ bucketBase, int* __restrict__ rowptr,
                            int N, int E, const float2* __restrict__ pmean, int nblk,
                            float invE,
                            const float* __restrict__ We1, const float* __restrict__ ae1,
                            const float* __restrict__ We2, const float* __restrict__ ae2,
                            const float* __restrict__ We3, const float* __restrict__ ae3,
                            float* __restrict__ park) {
    __shared__ int tmp[256];
    __shared__ float2 sp[4];
    __shared__ float smean[2];
    int t = threadIdx.x;  // 256
    float ax = 0.f, ay = 0.f;
    for (int i = t; i < nblk; i += 256) {
        float2 z = pmean[i];
        ax += z.x; ay += z.y;
    }
    ax = wred_sum(ax); ay = wred_sum(ay);
    if ((t & 63) == 0) sp[t >> 6] = make_float2(ax, ay);
    int v = (t < nbuckets) ? bucketTotal[t] : 0;
    tmp[t] = v;
    __syncthreads();
    for (int off = 1; off < 256; off <<= 1) {
        int q = (t >= off) ? tmp[t - off] : 0;
        __syncthreads();
        tmp[t] += q;
        __syncthreads();
    }
    bucketBase[t] = tmp[t] - v;  // exclusive; entries >= nbuckets hold E
    if (t == 0) {
        bucketBase[256] = tmp[255];  // == E
        rowptr[N] = E;
        smean[0] = (sp[0].x + sp[1].x + sp[2].x + sp[3].x) * invE;
        smean[1] = (sp[0].y + sp[1].y + sp[2].y + sp[3].y) * invE;
    }
    __syncthreads();
    if (t < 192) {
        int l = t >> 6, q = t & 63;
        const float* We = (l == 0) ? We1 : ((l == 1) ? We2 : We3);
        const float* ae = (l == 0) ? ae1 : ((l == 1) ? ae2 : ae3);
        float p0 = We[q] * ae[q] + We[q + 64] * ae[q + 64];
        float p1 = We[H + q] * ae[q] + We[H + q + 64] * ae[q + 64];
        p0 = wred_sum(p0);
        p1 = wred_sum(p1);
        if (q == 0) {
            park[l * 3 + 0] = p0;
            park[l * 3 + 1] = p1;
            park[l * 3 + 2] = smean[0] * p0 + smean[1] * p1;
        }
    }
}

// ---- Kernel B: place || gemm(layer 1) (independent roles) ------------------
__global__ void k_fusedB(const int* __restrict__ ei, const float* __restrict__ ea,
                         int E, int nblk, int nbuckets,
                         const int* __restrict__ bucketBase, const int* __restrict__ blockBase,
                         uint2* __restrict__ temp,
                         const ushort* __restrict__ hb, const ushort* __restrict__ Wp,
                         const float* __restrict__ avs, const float* __restrict__ avd,
                         ushort* __restrict__ gb, float* __restrict__ a_src,
                         float* __restrict__ a_dst, int N) {
    __shared__ int cnt[256];
    __shared__ int sbase[256];
    __shared__ ushort hs[64 * 136];
    const int tid = threadIdx.x;  // 256

    if (blockIdx.x < nblk) {
        int blk = blockIdx.x;
        cnt[tid] = 0;
        if (tid < nbuckets) sbase[tid] = bucketBase[tid] + blockBase[tid * nblk + blk];
        __syncthreads();
        int base = blk * EPB;
#pragma unroll
        for (int i = 0; i < 16; ++i) {
            int e = base + i * 256 + tid;
            if (e < E) {
                int s = ei[e];          // s < 65536 (N=50000)
                int d = ei[E + e];
                int b = d >> 8;
                int r = atomicAdd(&cnt[b], 1);
                const float2 z = *(const float2*)(ea + 2 * (size_t)e);
                uint w0 = (uint)s | ((uint)(d & 255) << 16);
                uint w1 = (uint)f2bf(z.x) | ((uint)f2bf(z.y) << 16);
                temp[sbase[b] + r] = make_uint2(w0, w1);
            }
        }
        return;
    }

    // ---- gemm layer 1 ----
    int nb = (blockIdx.x - nblk) * 64;
#pragma unroll
    for (int it = 0; it < 4; ++it) {
        int fi = it * 256 + tid;
        int r = fi >> 4;
        int c8 = (fi & 15) * 8;
        int node = nb + r;
        uint4 v = make_uint4(0, 0, 0, 0);
        if (node < N) v = *(const uint4*)(hb + (size_t)node * H + c8);
        *(uint4*)(hs + r * 136 + c8) = v;
    }
    __syncthreads();
    const int l = tid & 63;
    const int w = tid >> 6;
    const int cl = l & 15;
    const int kg = l >> 4;
    const ushort* hrow = hs + (w * 16 + cl) * 136 + kg * 8;
    short8v a0 = *(const short8v*)(hrow + 0);
    short8v a1 = *(const short8v*)(hrow + 32);
    short8v a2 = *(const short8v*)(hrow + 64);
    short8v a3 = *(const short8v*)(hrow + 96);

    f32x4 acc[8];
#pragma unroll
    for (int nt = 0; nt < 8; ++nt) {
        const short8v* bp = (const short8v*)(Wp + ((size_t)(nt * 4) * 64 + l) * 8);
        f32x4 c = {0.f, 0.f, 0.f, 0.f};
        c = __builtin_amdgcn_mfma_f32_16x16x32_bf16(a0, bp[0], c, 0, 0, 0);
        c = __builtin_amdgcn_mfma_f32_16x16x32_bf16(a1, bp[64], c, 0, 0, 0);
        c = __builtin_amdgcn_mfma_f32_16x16x32_bf16(a2, bp[128], c, 0, 0, 0);
        c = __builtin_amdgcn_mfma_f32_16x16x32_bf16(a3, bp[192], c, 0, 0, 0);
        acc[nt] = c;
    }

    float ps0 = 0.f, ps1 = 0.f, ps2 = 0.f, ps3 = 0.f;
    float pd0 = 0.f, pd1 = 0.f, pd2 = 0.f, pd3 = 0.f;
#pragma unroll
    for (int nt = 0; nt < 8; ++nt) {
        float vs = avs[cl + 16 * nt];
        float vd = avd[cl + 16 * nt];
        ps0 = fmaf(acc[nt].x, vs, ps0); pd0 = fmaf(acc[nt].x, vd, pd0);
        ps1 = fmaf(acc[nt].y, vs, ps1); pd1 = fmaf(acc[nt].y, vd, pd1);
        ps2 = fmaf(acc[nt].z, vs, ps2); pd2 = fmaf(acc[nt].z, vd, pd2);
        ps3 = fmaf(acc[nt].w, vs, ps3); pd3 = fmaf(acc[nt].w, vd, pd3);
    }
#pragma unroll
    for (int m = 8; m >= 1; m >>= 1) {
        ps0 += __shfl_xor(ps0, m, 64); pd0 += __shfl_xor(pd0, m, 64);
        ps1 += __shfl_xor(ps1, m, 64); pd1 += __shfl_xor(pd1, m, 64);
        ps2 += __shfl_xor(ps2, m, 64); pd2 += __shfl_xor(pd2, m, 64);
        ps3 += __shfl_xor(ps3, m, 64); pd3 += __shfl_xor(pd3, m, 64);
    }
    int r0 = nb + w * 16 + kg * 4;
    if (cl == 0) {
        if (r0 + 0 < N) { a_src[r0 + 0] = ps0; a_dst[r0 + 0] = pd0; }
        if (r0 + 1 < N) { a_src[r0 + 1] = ps1; a_dst[r0 + 1] = pd1; }
        if (r0 + 2 < N) { a_src[r0 + 2] = ps2; a_dst[r0 + 2] = pd2; }
        if (r0 + 3 < N) { a_src[r0 + 3] = ps3; a_dst[r0 + 3] = pd3; }
    }
#pragma unroll
    for (int nt = 0; nt < 8; ++nt) {
        int col = nt * 16 + cl;
        if (r0 + 0 < N) gb[(size_t)(r0 + 0) * H + col] = f2bf(acc[nt].x);
        if (r0 + 1 < N) gb[(size_t)(r0 + 1) * H + col] = f2bf(acc[nt].y);
        if (r0 + 2 < N) gb[(size_t)(r0 + 2) * H + col] = f2bf(acc[nt].z);
        if (r0 + 3 < N) gb[(size_t)(r0 + 3) * H + col] = f2bf(acc[nt].w);
    }
}

// K4: per-bucket fine CSR; emit rowptr + 3 per-layer 4B records {src, bf16 ae}
__global__ void k_fine(const uint2* __restrict__ temp, const int* __restrict__ bucketBase,
                       const float* __restrict__ park, int N,
                       uint* __restrict__ er0, uint* __restrict__ er1,
                       uint* __restrict__ er2, int* __restrict__ rowptr) {
    __shared__ int hist[256];
    __shared__ int tmp[256];
    __shared__ int fb[256];
    __shared__ int cur[256];
    int b = blockIdx.x;
    int t = threadIdx.x;  // 256
    const int lo = bucketBase[b], hi = bucketBase[b + 1];
    hist[t] = 0;
    __syncthreads();
    for (int e = lo + t; e < hi; e += 256) {
        atomicAdd(&hist[(temp[e].x >> 16) & 255], 1);
    }
    __syncthreads();
    int v = hist[t];
    tmp[t] = v;
    __syncthreads();
    for (int off = 1; off < 256; off <<= 1) {
        int q = (t >= off) ? tmp[t - off] : 0;
        __syncthreads();
        tmp[t] += q;
        __syncthreads();
    }
    fb[t] = tmp[t] - v;  // exclusive within bucket
    cur[t] = 0;
    int dst = b * 256 + t;
    if (dst < N) rowptr[dst] = lo + fb[t];
    __syncthreads();
    const float c00 = park[0], c01 = park[1];
    const float c10 = park[3], c11 = park[4];
    const float c20 = park[6], c21 = park[7];
    for (int e = lo + t; e < hi; e += 256) {
        uint2 w = temp[e];
        uint src = w.x & 0xFFFFu;
        int j = (int)((w.x >> 16) & 255u);
        float ex = __uint_as_float(w.y << 16);
        float ey = __uint_as_float(w.y & 0xffff0000u);
        int r = atomicAdd(&cur[j], 1);
        int p = lo + fb[j] + r;
        er0[p] = src | ((uint)f2bf(c00 * ex + c01 * ey) << 16);
        er1[p] = src | ((uint)f2bf(c10 * ex + c11 * ey) << 16);
        er2[p] = src | ((uint)f2bf(c20 * ex + c21 * ey) << 16);
    }
}

// ---- per-layer GEMM (standalone, layers 2/3) -------------------------------
__global__ void k_gemm_mfma(const ushort* __restrict__ hb, const ushort* __restrict__ Wp,
                            const float* __restrict__ avs, const float* __restrict__ avd,
                            ushort* __restrict__ gb, float* __restrict__ a_src,
                            float* __restrict__ a_dst, int N) {
    __shared__ ushort hs[64 * 136];
    int tid = threadIdx.x;
    int nb = blockIdx.x * 64;
#pragma unroll
    for (int it = 0; it < 4; ++it) {
        int fi = it * 256 + tid;
        int r = fi >> 4;
        int c8 = (fi & 15) * 8;
        int node = nb + r;
        uint4 v = make_uint4(0, 0, 0, 0);
        if (node < N) v = *(const uint4*)(hb + (size_t)node * H + c8);
        *(uint4*)(hs + r * 136 + c8) = v;
    }
    __syncthreads();
    const int l = tid & 63;
    const int w = tid >> 6;
    const int cl = l & 15;
    const int kg = l >> 4;
    const ushort* hrow = hs + (w * 16 + cl) * 136 + kg * 8;
    short8v a0 = *(const short8v*)(hrow + 0);
    short8v a1 = *(const short8v*)(hrow + 32);
    short8v a2 = *(const short8v*)(hrow + 64);
    short8v a3 = *(const short8v*)(hrow + 96);

    f32x4 acc[8];
#pragma unroll
    for (int nt = 0; nt < 8; ++nt) {
        const short8v* bp = (const short8v*)(Wp + ((size_t)(nt * 4) * 64 + l) * 8);
        f32x4 c = {0.f, 0.f, 0.f, 0.f};
        c = __builtin_amdgcn_mfma_f32_16x16x32_bf16(a0, bp[0], c, 0, 0, 0);
        c = __builtin_amdgcn_mfma_f32_16x16x32_bf16(a1, bp[64], c, 0, 0, 0);
        c = __builtin_amdgcn_mfma_f32_16x16x32_bf16(a2, bp[128], c, 0, 0, 0);
        c = __builtin_amdgcn_mfma_f32_16x16x32_bf16(a3, bp[192], c, 0, 0, 0);
        acc[nt] = c;
    }

    float ps0 = 0.f, ps1 = 0.f, ps2 = 0.f, ps3 = 0.f;
    float pd0 = 0.f, pd1 = 0.f, pd2 = 0.f, pd3 = 0.f;
#pragma unroll
    for (int nt = 0; nt < 8; ++nt) {
        float vs = avs[cl + 16 * nt];
        float vd = avd[cl + 16 * nt];
        ps0 = fmaf(acc[nt].x, vs, ps0); pd0 = fmaf(acc[nt].x, vd, pd0);
        ps1 = fmaf(acc[nt].y, vs, ps1); pd1 = fmaf(acc[nt].y, vd, pd1);
        ps2 = fmaf(acc[nt].z, vs, ps2); pd2 = fmaf(acc[nt].z, vd, pd2);
        ps3 = fmaf(acc[nt].w, vs, ps3); pd3 = fmaf(acc[nt].w, vd, pd3);
    }
#pragma unroll
    for (int m = 8; m >= 1; m >>= 1) {
        ps0 += __shfl_xor(ps0, m, 64); pd0 += __shfl_xor(pd0, m, 64);
        ps1 += __shfl_xor(ps1, m, 64); pd1 += __shfl_xor(pd1, m, 64);
        ps2 += __shfl_xor(ps2, m, 64); pd2 += __shfl_xor(pd2, m, 64);
        ps3 += __shfl_xor(ps3, m, 64); pd3 += __shfl_xor(pd3, m, 64);
    }
    int r0 = nb + w * 16 + kg * 4;
    if (cl == 0) {
        if (r0 + 0 < N) { a_src[r0 + 0] = ps0; a_dst[r0 + 0] = pd0; }
        if (r0 + 1 < N) { a_src[r0 + 1] = ps1; a_dst[r0 + 1] = pd1; }
        if (r0 + 2 < N) { a_src[r0 + 2] = ps2; a_dst[r0 + 2] = pd2; }
        if (r0 + 3 < N) { a_src[r0 + 3] = ps3; a_dst[r0 + 3] = pd3; }
    }
#pragma unroll
    for (int nt = 0; nt < 8; ++nt) {
        int col = nt * 16 + cl;
        if (r0 + 0 < N) gb[(size_t)(r0 + 0) * H + col] = f2bf(acc[nt].x);
        if (r0 + 1 < N) gb[(size_t)(r0 + 1) * H + col] = f2bf(acc[nt].y);
        if (r0 + 2 < N) gb[(size_t)(r0 + 2) * H + col] = f2bf(acc[nt].z);
        if (r0 + 3 < N) gb[(size_t)(r0 + 3) * H + col] = f2bf(acc[nt].w);
    }
}

// ---- phase 1: online softmax stats per node (m, 1/s) -----------------------
__global__ void k_soft(const float* __restrict__ a_src, const float* __restrict__ a_dst,
                       const int* __restrict__ rowptr, const uint* __restrict__ erecL,
                       const float* __restrict__ park, int layer,
                       float* __restrict__ sm, float* __restrict__ sis, int N) {
    int wv = threadIdx.x >> 6;
    int lane = threadIdx.x & 63;
    int v = blockIdx.x * 4 + wv;
    if (v >= N) return;

    const float sa = park[layer * 3 + 2];
    const float adv = a_dst[v];
    float lself = a_src[v] + adv + sa;
    lself = (lself > 0.f) ? lself : 0.2f * lself;

    float m = lself;
    float s = 1.f;  // self weight exp(0)
    const int rs = rowptr[v];
    const int re = rowptr[v + 1];
    for (int p0 = rs; p0 < re; p0 += 64) {
        int e = p0 + lane;
        bool val = e < re;
        uint rec = val ? __builtin_nontemporal_load(erecL + e) : 0u;
        int sv = (int)(rec & 0xFFFFu);
        float lg;
        if (val) {
            float aef = __uint_as_float(rec & 0xffff0000u);
            lg = a_src[sv] + adv + aef;
            lg = (lg > 0.f) ? lg : 0.2f * lg;
        } else {
            lg = -INFINITY;
        }
        float cm = wred_max(lg);
        float nm = fmaxf(m, cm);
        float f = __expf(m - nm);
        float w = val ? __expf(lg - nm) : 0.f;
        float ws = wred_sum(w);
        s = s * f + ws;
        m = nm;
    }
    if (lane == 0) {
        sm[v] = m;
        sis[v] = 1.f / s;
    }
}

// ---- phase 2: sliced gather. slice = blockIdx&3 -> one 3.2MB slice per XCD -
// Wave per (node, slice): 16 edge-groups x 4 lanes x 16B (8 bf16 ch each).
// MODE 0: relu, bf16 out. MODE 1: +h0 residual, fp32 out.
template <int MODE>
__global__ void k_gath(const ushort* __restrict__ gb, const float* __restrict__ a_src,
                       const float* __restrict__ a_dst, const int* __restrict__ rowptr,
                       const uint* __restrict__ erecL, const float* __restrict__ park,
                       int layer, const float* __restrict__ sm, const float* __restrict__ sis,
                       const float* __restrict__ bias, const float* __restrict__ h0,
                       float* __restrict__ outf, ushort* __restrict__ outb, int N) {
    const int sl = blockIdx.x & 3;
    const int wv = threadIdx.x >> 6;
    const int lane = threadIdx.x & 63;
    const int v = (blockIdx.x >> 2) * 4 + wv;
    if (v >= N) return;

    const int grp = lane >> 2;       // 16 edge slots
    const int sub = lane & 3;        // 4 lanes per edge
    const int ch8 = sl * 32 + sub * 8;

    const float sa = park[layer * 3 + 2];
    const float adv = a_dst[v];
    const float mv = sm[v];
    float lself = a_src[v] + adv + sa;
    lself = (lself > 0.f) ? lself : 0.2f * lself;
    const float wself = __expf(lself - mv);

    float acc[8];
    {
        const uint4 q = *(const uint4*)(gb + (size_t)v * H + ch8);
        float sel = (grp == 0) ? wself : 0.f;
        acc[0] = sel * bflo(q.x); acc[1] = sel * bfhi(q.x);
        acc[2] = sel * bflo(q.y); acc[3] = sel * bfhi(q.y);
        acc[4] = sel * bflo(q.z); acc[5] = sel * bfhi(q.z);
        acc[6] = sel * bflo(q.w); acc[7] = sel * bfhi(q.w);
    }

#define ACC8(W, Q)                                     \
    acc[0] = fmaf(W, bflo(Q.x), acc[0]);               \
    acc[1] = fmaf(W, bfhi(Q.x), acc[1]);               \
    acc[2] = fmaf(W, bflo(Q.y), acc[2]);               \
    acc[3] = fmaf(W, bfhi(Q.y), acc[3]);               \
    acc[4] = fmaf(W, bflo(Q.z), acc[4]);               \
    acc[5] = fmaf(W, bfhi(Q.z), acc[5]);               \
    acc[6] = fmaf(W, bflo(Q.w), acc[6]);               \
    acc[7] = fmaf(W, bfhi(Q.w), acc[7]);

    const int rs = rowptr[v];
    const int re = rowptr[v + 1];
    for (int p0 = rs; p0 < re; p0 += 64) {
        int e = p0 + lane;
        bool val = e < re;
        uint rec = val ? __builtin_nontemporal_load(erecL + e) : 0u;
        int sv = (int)(rec & 0xFFFFu);
        float w = 0.f;
        if (val) {
            float aef = __uint_as_float(rec & 0xffff0000u);
            float lg = a_src[sv] + adv + aef;
            lg = (lg > 0.f) ? lg : 0.2f * lg;
            w = __expf(lg - mv);   // no reductions: m is final
        }
        int cnt = re - p0;
        if (cnt > 64) cnt = 64;
        const int cm1 = cnt - 1;

        int j0 = grp,      j0c = (j0 <= cm1) ? j0 : cm1;
        int j1 = grp + 16, j1c = (j1 <= cm1) ? j1 : cm1;
        int j2 = grp + 32, j2c = (j2 <= cm1) ? j2 : cm1;
        int j3 = grp + 48, j3c = (j3 <= cm1) ? j3 : cm1;
        float w0 = __shfl(w, j0c, 64); if (j0 > cm1) w0 = 0.f;
        float w1 = __shfl(w, j1c, 64); if (j1 > cm1) w1 = 0.f;
        float w2 = __shfl(w, j2c, 64); if (j2 > cm1) w2 = 0.f;
        float w3 = __shfl(w, j3c, 64); if (j3 > cm1) w3 = 0.f;
        int s0 = __shfl(sv, j0c, 64);
        int s1 = __shfl(sv, j1c, 64);
        int s2 = __shfl(sv, j2c, 64);
        int s3 = __shfl(sv, j3c, 64);
        // 4 independent L2-resident loads in flight
        const uint4 q0 = *(const uint4*)(gb + (size_t)s0 * H + ch8);
        const uint4 q1 = *(const uint4*)(gb + (size_t)s1 * H + ch8);
        const uint4 q2 = *(const uint4*)(gb + (size_t)s2 * H + ch8);
        const uint4 q3 = *(const uint4*)(gb + (size_t)s3 * H + ch8);
        ACC8(w0, q0);
        ACC8(w1, q1);
        ACC8(w2, q2);
        ACC8(w3, q3);
    }
#undef ACC8

    // combine the 16 edge-group partials (sub stays fixed under these masks)
#pragma unroll
    for (int k = 0; k < 8; ++k) {
        acc[k] += __shfl_xor(acc[k], 4, 64);
        acc[k] += __shfl_xor(acc[k], 8, 64);
        acc[k] += __shfl_xor(acc[k], 16, 64);
        acc[k] += __shfl_xor(acc[k], 32, 64);
    }

    if (grp == 0) {
        const float is = sis[v];
        const float4 b0 = *(const float4*)(bias + ch8);
        const float4 b1 = *(const float4*)(bias + ch8 + 4);
        float o[8];
        o[0] = acc[0] * is + b0.x; o[1] = acc[1] * is + b0.y;
        o[2] = acc[2] * is + b0.z; o[3] = acc[3] * is + b0.w;
        o[4] = acc[4] * is + b1.x; o[5] = acc[5] * is + b1.y;
        o[6] = acc[6] * is + b1.z; o[7] = acc[7] * is + b1.w;
        if (MODE == 0) {
#pragma unroll
            for (int k = 0; k < 8; ++k) o[k] = fmaxf(o[k], 0.f);
            uint4 ob;
            ob.x = (uint)f2bf(o[0]) | ((uint)f2bf(o[1]) << 16);
            ob.y = (uint)f2bf(o[2]) | ((uint)f2bf(o[3]) << 16);
            ob.z = (uint)f2bf(o[4]) | ((uint)f2bf(o[5]) << 16);
            ob.w = (uint)f2bf(o[6]) | ((uint)f2bf(o[7]) << 16);
            *(uint4*)(outb + (size_t)v * H + ch8) = ob;
        } else {
            const float4 ha = *(const float4*)(h0 + (size_t)v * H + ch8);
            const float4 hb4 = *(const float4*)(h0 + (size_t)v * H + ch8 + 4);
            o[0] += ha.x; o[1] += ha.y; o[2] += ha.z; o[3] += ha.w;
            o[4] += hb4.x; o[5] += hb4.y; o[6] += hb4.z; o[7] += hb4.w;
            *(float4*)(outf + (size_t)v * H + ch8) = make_float4(o[0], o[1], o[2], o[3]);
            *(float4*)(outf + (size_t)v * H + ch8 + 4) = make_float4(o[4], o[5], o[6], o[7]);
        }
    }
}

// ---------------------------------------------------------------------------

extern "C" void kernel_launch(void* const* d_in, const int* in_sizes, int n_in,
                              void* d_out, int out_size, void* d_ws, size_t ws_size,
                              hipStream_t stream) {
    const float* x    = (const float*)d_in[0];
    const int*   ei   = (const int*)d_in[1];
    const float* ea   = (const float*)d_in[2];
    const float* encW = (const float*)d_in[3];
    const float* encb = (const float*)d_in[4];
    const float* bng  = (const float*)d_in[5];
    const float* bnb  = (const float*)d_in[6];
    const float *W[3], *asrc[3], *adst[3], *We[3], *aev[3], *bias[3];
    for (int l = 0; l < 3; ++l) {
        W[l]    = (const float*)d_in[7 + l * 6 + 0];
        asrc[l] = (const float*)d_in[7 + l * 6 + 1];
        adst[l] = (const float*)d_in[7 + l * 6 + 2];
        We[l]   = (const float*)d_in[7 + l * 6 + 3];
        aev[l]  = (const float*)d_in[7 + l * 6 + 4];
        bias[l] = (const float*)d_in[7 + l * 6 + 5];
    }
    const int N = in_sizes[0] / NF;   // 50000 (< 65536: src packs in 16 bits)
    const int E = in_sizes[1] / 2;
    float* out = (float*)d_out;

    const int NBu  = (N + 255) >> 8;          // coarse buckets (196)
    const int nblk = (E + EPB - 1) / EPB;     // count/place blocks (391)
    const int GB8  = (N + 7) / 8;             // encoder blocks
    const int GBM  = (N + 63) / 64;           // gemm blocks
    const int AB   = (N + 3) / 4;             // soft blocks
    const int AB4  = AB * 4;                  // gath blocks (4 slices)

    // workspace carve-up (256B aligned)
    char* wp = (char*)d_ws;
    auto alloc = [&](size_t bytes) -> char* {
        char* p = wp;
        wp += (bytes + 255) & ~(size_t)255;
        return p;
    };
    float*  h0       = (float*)alloc((size_t)N * H * 4);
    ushort* hb       = (ushort*)alloc((size_t)N * H * 2);
    ushort* gb       = (ushort*)alloc((size_t)N * H * 2);
    ushort* Wp       = (ushort*)alloc((size_t)3 * 16384 * 2);
    float*  a_src    = (float*)alloc((size_t)N * 4);
    float*  a_dst    = (float*)alloc((size_t)N * 4);
    float*  sm       = (float*)alloc((size_t)N * 4);
    float*  sis      = (float*)alloc((size_t)N * 4);
    int*    rowptr   = (int*)alloc((size_t)(N + 1) * 4);
    float*  park     = (float*)alloc(64);
    int*    bucketTotal = (int*)alloc(256 * 4);
    int*    bucketBase  = (int*)alloc(257 * 4);
    int*    blockBase   = (int*)alloc((size_t)NBu * nblk * 4);
    uint*   er0      = (uint*)alloc((size_t)E * 4);
    uint*   er1      = (uint*)alloc((size_t)E * 4);
    uint*   er2      = (uint*)alloc((size_t)E * 4);
    float2* pmean    = (float2*)alloc((size_t)nblk * 8);
    uint2*  temp     = (uint2*)alloc((size_t)E * 8);

    hipMemsetAsync(bucketTotal, 0, 256 * 4, stream);

    // A: count || encoder || wpack
    k_fusedA<<<nblk + GB8 + 3, 256, 0, stream>>>(
        ei, ea, E, nblk, NBu, bucketTotal, blockBase, pmean,
        x, encW, encb, bng, bnb, h0, hb, N, GB8,
        W[0], W[1], W[2], Wp);
    k_scan_park<<<1, 256, 0, stream>>>(bucketTotal, NBu, bucketBase, rowptr, N, E,
                                       pmean, nblk, 1.0f / (float)E,
                                       We[0], aev[0], We[1], aev[1], We[2], aev[2], park);
    // B: place || gemm layer 1
    k_fusedB<<<nblk + GBM, 256, 0, stream>>>(
        ei, ea, E, nblk, NBu, bucketBase, blockBase, temp,
        hb, Wp + 0 * 16384, asrc[0], adst[0], gb, a_src, a_dst, N);
    k_fine<<<NBu, 256, 0, stream>>>(temp, bucketBase, park, N, er0, er1, er2, rowptr);

    // layer 1: soft + sliced gather -> hb
    k_soft<<<AB, 256, 0, stream>>>(a_src, a_dst, rowptr, er0, park, 0, sm, sis, N);
    k_gath<0><<<AB4, 256, 0, stream>>>(gb, a_src, a_dst, rowptr, er0, park, 0,
                                       sm, sis, bias[0], nullptr, nullptr, hb, N);
    // layer 2
    k_gemm_mfma<<<GBM, 256, 0, stream>>>(hb, Wp + 1 * 16384, asrc[1], adst[1],
                                         gb, a_src, a_dst, N);
    k_soft<<<AB, 256, 0, stream>>>(a_src, a_dst, rowptr, er1, park, 1, sm, sis, N);
    k_gath<0><<<AB4, 256, 0, stream>>>(gb, a_src, a_dst, rowptr, er1, park, 1,
                                       sm, sis, bias[1], nullptr, nullptr, hb, N);
    // layer 3: out = agg + h0 (fp32)
    k_gemm_mfma<<<GBM, 256, 0, stream>>>(hb, Wp + 2 * 16384, asrc[2], adst[2],
                                         gb, a_src, a_dst, N);
    k_soft<<<AB, 256, 0, stream>>>(a_src, a_dst, rowptr, er2, park, 2, sm, sis, N);
    k_gath<1><<<AB4, 256, 0, stream>>>(gb, a_src, a_dst, rowptr, er2, park, 2,
                                       sm, sis, bias[2], h0, out, nullptr, N);
}

// Round 11
// 290.315 us; speedup vs baseline: 1.8156x; 1.8156x over previous
//
#include <hip/hip_runtime.h>
#include <math.h>

// ---------------------------------------------------------------------------
// ImprovedCrossBorderGNN: 3-layer edge-conditioned GAT, N=50000, E=1.6M, H=128
// CSR (dst-grouped) built once; per layer: bf16 MFMA GEMM g=h@W (fused
// a_src/a_dst epilogue), then wave-per-node online-softmax gather.
// R1: mean() via two-stage reduction. R2: bf16 g; parallel scans.
// R4: CSR via two-level counting sort. R5: register-blocked GEMM.
// R6/R7: 16B-wide pipelined gather; agg at the ~3.3TB/s random-gather L3
//        service ceiling (12.8MB table vs 4MB/XCD L2; ~59% hit).
// R8: MFMA bf16 GEMM; 4B/edge/layer records; bf16 hidden states.
// R9: serial-chain fusion (A = count||encoder||wpack, B = place||gemm1).
// R10: channel-slice experiment FAILED (527us): blockIdx&3 does not pin
//      slices to XCDs; 4x edge-stream re-reads. Reverted.
// R11: R9 structure + R8 agg body (f32x2/nontemporal micro-opts dropped:
//      they cost VGPR 32->36, occupancy 70->63%, +2us).
// ---------------------------------------------------------------------------

#define H 128
#define NF 8
#define EPB 4096  // edges per block in count/place (256 threads x 16)

typedef __attribute__((ext_vector_type(8))) short short8v;
typedef __attribute__((ext_vector_type(4))) float f32x4;

__device__ __forceinline__ float wred_sum(float x) {
#pragma unroll
    for (int m = 32; m >= 1; m >>= 1) x += __shfl_xor(x, m, 64);
    return x;
}
__device__ __forceinline__ float wred_max(float x) {
#pragma unroll
    for (int m = 32; m >= 1; m >>= 1) x = fmaxf(x, __shfl_xor(x, m, 64));
    return x;
}
__device__ __forceinline__ ushort f2bf(float f) {
    uint u = __float_as_uint(f);
    uint r = (u + 0x7FFFu + ((u >> 16) & 1u)) >> 16;  // round-to-nearest-even
    return (ushort)r;
}

// ---- Kernel A: count || encoder || wpack (independent roles) ---------------
__global__ void k_fusedA(const int* __restrict__ ei, const float* __restrict__ ea,
                         int E, int nblk, int nbuckets, int* __restrict__ bucketTotal,
                         int* __restrict__ blockBase, float2* __restrict__ pmean,
                         const float* __restrict__ x, const float* __restrict__ encW,
                         const float* __restrict__ encb, const float* __restrict__ bng,
                         const float* __restrict__ bnb, float* __restrict__ h0,
                         ushort* __restrict__ hb, int N, int GB8,
                         const float* __restrict__ W1, const float* __restrict__ W2,
                         const float* __restrict__ W3, ushort* __restrict__ Wp) {
    __shared__ int hist[256];
    __shared__ float sx[4], sy[4];
    __shared__ float xs[8 * NF];
    const int bx = blockIdx.x;
    const int t = threadIdx.x;  // 256

    if (bx < nblk) {
        int blk = bx;
        hist[t] = 0;
        __syncthreads();
        int base = blk * EPB;
        float px = 0.f, py = 0.f;
#pragma unroll
        for (int i = 0; i < 16; ++i) {
            int e = base + i * 256 + t;
            if (e < E) {
                int d = ei[E + e];
                atomicAdd(&hist[d >> 8], 1);
                const float2 z = *(const float2*)(ea + 2 * (size_t)e);
                px += z.x; py += z.y;
            }
        }
        px = wred_sum(px); py = wred_sum(py);
        if ((t & 63) == 0) { sx[t >> 6] = px; sy[t >> 6] = py; }
        __syncthreads();
        if (t == 0) {
            pmean[blk] = make_float2(sx[0] + sx[1] + sx[2] + sx[3],
                                     sy[0] + sy[1] + sy[2] + sy[3]);
        }
        if (t < nbuckets) {
            int c = hist[t];
            int old = (c > 0) ? atomicAdd(&bucketTotal[t], c) : 0;
            blockBase[t * nblk + blk] = old;
        }
    } else if (bx < nblk + GB8) {
        int nb = (bx - nblk) * 8;
        if (t < 64) {
            size_t idx = (size_t)nb * NF + t;
            xs[t] = (idx < (size_t)N * NF) ? x[idx] : 0.f;
        }
        __syncthreads();
        int jt = t & 31, i = t >> 5;
        int node = nb + i;
        int j4 = jt * 4;
        float ax = 0.f, ay = 0.f, az = 0.f, aw = 0.f;
#pragma unroll
        for (int k = 0; k < NF; ++k) {
            float hx = xs[i * NF + k];
            const float4 w = *(const float4*)(encW + k * H + j4);
            ax = fmaf(hx, w.x, ax); ay = fmaf(hx, w.y, ay);
            az = fmaf(hx, w.z, az); aw = fmaf(hx, w.w, aw);
        }
        if (node < N) {
            const float inv = 0.9999950000374997f;  // 1/sqrt(1+1e-5)
            const float4 eb = *(const float4*)(encb + j4);
            const float4 gg = *(const float4*)(bng + j4);
            const float4 bb = *(const float4*)(bnb + j4);
            float4 o;
            o.x = fmaxf(0.f, (ax + eb.x) * (gg.x * inv) + bb.x);
            o.y = fmaxf(0.f, (ay + eb.y) * (gg.y * inv) + bb.y);
            o.z = fmaxf(0.f, (az + eb.z) * (gg.z * inv) + bb.z);
            o.w = fmaxf(0.f, (aw + eb.w) * (gg.w * inv) + bb.w);
            *(float4*)(h0 + (size_t)node * H + j4) = o;
            uint2 ob;
            ob.x = (uint)f2bf(o.x) | ((uint)f2bf(o.y) << 16);
            ob.y = (uint)f2bf(o.z) | ((uint)f2bf(o.w) << 16);
            *(uint2*)(hb + (size_t)node * H + j4) = ob;
        }
    } else {
        int layer = bx - nblk - GB8;
        const float* W = (layer == 0) ? W1 : ((layer == 1) ? W2 : W3);
        for (int idx = t; idx < 16384; idx += 256) {
            int i = idx & 7;
            int lane = (idx >> 3) & 63;
            int ft = idx >> 9;
            int kt = ft & 3, nt = ft >> 2;
            int k = kt * 32 + (lane >> 4) * 8 + i;
            int n = nt * 16 + (lane & 15);
            Wp[layer * 16384 + idx] = f2bf(W[k * H + n]);
        }
    }
}

// ---- scan + park (1 block) -------------------------------------------------
__global__ void k_scan_park(const int* __restrict__ bucketTotal, int nbuckets,
                            int* __restrict__ bucketBase, int* __restrict__ rowptr,
                            int N, int E, const float2* __restrict__ pmean, int nblk,
                            float invE,
                            const float* __restrict__ We1, const float* __restrict__ ae1,
                            const float* __restrict__ We2, const float* __restrict__ ae2,
                            const float* __restrict__ We3, const float* __restrict__ ae3,
                            float* __restrict__ park) {
    __shared__ int tmp[256];
    __shared__ float2 sp[4];
    __shared__ float smean[2];
    int t = threadIdx.x;  // 256
    float ax = 0.f, ay = 0.f;
    for (int i = t; i < nblk; i += 256) {
        float2 z = pmean[i];
        ax += z.x; ay += z.y;
    }
    ax = wred_sum(ax); ay = wred_sum(ay);
    if ((t & 63) == 0) sp[t >> 6] = make_float2(ax, ay);
    int v = (t < nbuckets) ? bucketTotal[t] : 0;
    tmp[t] = v;
    __syncthreads();
    for (int off = 1; off < 256; off <<= 1) {
        int q = (t >= off) ? tmp[t - off] : 0;
        __syncthreads();
        tmp[t] += q;
        __syncthreads();
    }
    bucketBase[t] = tmp[t] - v;  // exclusive; entries >= nbuckets hold E
    if (t == 0) {
        bucketBase[256] = tmp[255];  // == E
        rowptr[N] = E;
        smean[0] = (sp[0].x + sp[1].x + sp[2].x + sp[3].x) * invE;
        smean[1] = (sp[0].y + sp[1].y + sp[2].y + sp[3].y) * invE;
    }
    __syncthreads();
    if (t < 192) {
        int l = t >> 6, q = t & 63;
        const float* We = (l == 0) ? We1 : ((l == 1) ? We2 : We3);
        const float* ae = (l == 0) ? ae1 : ((l == 1) ? ae2 : ae3);
        float p0 = We[q] * ae[q] + We[q + 64] * ae[q + 64];
        float p1 = We[H + q] * ae[q] + We[H + q + 64] * ae[q + 64];
        p0 = wred_sum(p0);
        p1 = wred_sum(p1);
        if (q == 0) {
            park[l * 3 + 0] = p0;
            park[l * 3 + 1] = p1;
            park[l * 3 + 2] = smean[0] * p0 + smean[1] * p1;
        }
    }
}

// ---- Kernel B: place || gemm(layer 1) (independent roles) ------------------
__global__ void k_fusedB(const int* __restrict__ ei, const float* __restrict__ ea,
                         int E, int nblk, int nbuckets,
                         const int* __restrict__ bucketBase, const int* __restrict__ blockBase,
                         uint2* __restrict__ temp,
                         const ushort* __restrict__ hb, const ushort* __restrict__ Wp,
                         const float* __restrict__ avs, const float* __restrict__ avd,
                         ushort* __restrict__ gb, float* __restrict__ a_src,
                         float* __restrict__ a_dst, int N) {
    __shared__ int cnt[256];
    __shared__ int sbase[256];
    __shared__ ushort hs[64 * 136];
    const int tid = threadIdx.x;  // 256

    if (blockIdx.x < nblk) {
        int blk = blockIdx.x;
        cnt[tid] = 0;
        if (tid < nbuckets) sbase[tid] = bucketBase[tid] + blockBase[tid * nblk + blk];
        __syncthreads();
        int base = blk * EPB;
#pragma unroll
        for (int i = 0; i < 16; ++i) {
            int e = base + i * 256 + tid;
            if (e < E) {
                int s = ei[e];          // s < 65536 (N=50000)
                int d = ei[E + e];
                int b = d >> 8;
                int r = atomicAdd(&cnt[b], 1);
                const float2 z = *(const float2*)(ea + 2 * (size_t)e);
                uint w0 = (uint)s | ((uint)(d & 255) << 16);
                uint w1 = (uint)f2bf(z.x) | ((uint)f2bf(z.y) << 16);
                temp[sbase[b] + r] = make_uint2(w0, w1);
            }
        }
        return;
    }

    // ---- gemm layer 1 ----
    int nb = (blockIdx.x - nblk) * 64;
#pragma unroll
    for (int it = 0; it < 4; ++it) {
        int fi = it * 256 + tid;
        int r = fi >> 4;
        int c8 = (fi & 15) * 8;
        int node = nb + r;
        uint4 v = make_uint4(0, 0, 0, 0);
        if (node < N) v = *(const uint4*)(hb + (size_t)node * H + c8);
        *(uint4*)(hs + r * 136 + c8) = v;
    }
    __syncthreads();
    const int l = tid & 63;
    const int w = tid >> 6;
    const int cl = l & 15;
    const int kg = l >> 4;
    const ushort* hrow = hs + (w * 16 + cl) * 136 + kg * 8;
    short8v a0 = *(const short8v*)(hrow + 0);
    short8v a1 = *(const short8v*)(hrow + 32);
    short8v a2 = *(const short8v*)(hrow + 64);
    short8v a3 = *(const short8v*)(hrow + 96);

    f32x4 acc[8];
#pragma unroll
    for (int nt = 0; nt < 8; ++nt) {
        const short8v* bp = (const short8v*)(Wp + ((size_t)(nt * 4) * 64 + l) * 8);
        f32x4 c = {0.f, 0.f, 0.f, 0.f};
        c = __builtin_amdgcn_mfma_f32_16x16x32_bf16(a0, bp[0], c, 0, 0, 0);
        c = __builtin_amdgcn_mfma_f32_16x16x32_bf16(a1, bp[64], c, 0, 0, 0);
        c = __builtin_amdgcn_mfma_f32_16x16x32_bf16(a2, bp[128], c, 0, 0, 0);
        c = __builtin_amdgcn_mfma_f32_16x16x32_bf16(a3, bp[192], c, 0, 0, 0);
        acc[nt] = c;
    }

    float ps0 = 0.f, ps1 = 0.f, ps2 = 0.f, ps3 = 0.f;
    float pd0 = 0.f, pd1 = 0.f, pd2 = 0.f, pd3 = 0.f;
#pragma unroll
    for (int nt = 0; nt < 8; ++nt) {
        float vs = avs[cl + 16 * nt];
        float vd = avd[cl + 16 * nt];
        ps0 = fmaf(acc[nt].x, vs, ps0); pd0 = fmaf(acc[nt].x, vd, pd0);
        ps1 = fmaf(acc[nt].y, vs, ps1); pd1 = fmaf(acc[nt].y, vd, pd1);
        ps2 = fmaf(acc[nt].z, vs, ps2); pd2 = fmaf(acc[nt].z, vd, pd2);
        ps3 = fmaf(acc[nt].w, vs, ps3); pd3 = fmaf(acc[nt].w, vd, pd3);
    }
#pragma unroll
    for (int m = 8; m >= 1; m >>= 1) {
        ps0 += __shfl_xor(ps0, m, 64); pd0 += __shfl_xor(pd0, m, 64);
        ps1 += __shfl_xor(ps1, m, 64); pd1 += __shfl_xor(pd1, m, 64);
        ps2 += __shfl_xor(ps2, m, 64); pd2 += __shfl_xor(pd2, m, 64);
        ps3 += __shfl_xor(ps3, m, 64); pd3 += __shfl_xor(pd3, m, 64);
    }
    int r0 = nb + w * 16 + kg * 4;
    if (cl == 0) {
        if (r0 + 0 < N) { a_src[r0 + 0] = ps0; a_dst[r0 + 0] = pd0; }
        if (r0 + 1 < N) { a_src[r0 + 1] = ps1; a_dst[r0 + 1] = pd1; }
        if (r0 + 2 < N) { a_src[r0 + 2] = ps2; a_dst[r0 + 2] = pd2; }
        if (r0 + 3 < N) { a_src[r0 + 3] = ps3; a_dst[r0 + 3] = pd3; }
    }
#pragma unroll
    for (int nt = 0; nt < 8; ++nt) {
        int col = nt * 16 + cl;
        if (r0 + 0 < N) gb[(size_t)(r0 + 0) * H + col] = f2bf(acc[nt].x);
        if (r0 + 1 < N) gb[(size_t)(r0 + 1) * H + col] = f2bf(acc[nt].y);
        if (r0 + 2 < N) gb[(size_t)(r0 + 2) * H + col] = f2bf(acc[nt].z);
        if (r0 + 3 < N) gb[(size_t)(r0 + 3) * H + col] = f2bf(acc[nt].w);
    }
}

// K4: per-bucket fine CSR; emit rowptr + 3 per-layer 4B records {src, bf16 ae}
__global__ void k_fine(const uint2* __restrict__ temp, const int* __restrict__ bucketBase,
                       const float* __restrict__ park, int N,
                       uint* __restrict__ er0, uint* __restrict__ er1,
                       uint* __restrict__ er2, int* __restrict__ rowptr) {
    __shared__ int hist[256];
    __shared__ int tmp[256];
    __shared__ int fb[256];
    __shared__ int cur[256];
    int b = blockIdx.x;
    int t = threadIdx.x;  // 256
    const int lo = bucketBase[b], hi = bucketBase[b + 1];
    hist[t] = 0;
    __syncthreads();
    for (int e = lo + t; e < hi; e += 256) {
        atomicAdd(&hist[(temp[e].x >> 16) & 255], 1);
    }
    __syncthreads();
    int v = hist[t];
    tmp[t] = v;
    __syncthreads();
    for (int off = 1; off < 256; off <<= 1) {
        int q = (t >= off) ? tmp[t - off] : 0;
        __syncthreads();
        tmp[t] += q;
        __syncthreads();
    }
    fb[t] = tmp[t] - v;  // exclusive within bucket
    cur[t] = 0;
    int dst = b * 256 + t;
    if (dst < N) rowptr[dst] = lo + fb[t];
    __syncthreads();
    const float c00 = park[0], c01 = park[1];
    const float c10 = park[3], c11 = park[4];
    const float c20 = park[6], c21 = park[7];
    for (int e = lo + t; e < hi; e += 256) {
        uint2 w = temp[e];
        uint src = w.x & 0xFFFFu;
        int j = (int)((w.x >> 16) & 255u);
        float ex = __uint_as_float(w.y << 16);
        float ey = __uint_as_float(w.y & 0xffff0000u);
        int r = atomicAdd(&cur[j], 1);
        int p = lo + fb[j] + r;
        er0[p] = src | ((uint)f2bf(c00 * ex + c01 * ey) << 16);
        er1[p] = src | ((uint)f2bf(c10 * ex + c11 * ey) << 16);
        er2[p] = src | ((uint)f2bf(c20 * ex + c21 * ey) << 16);
    }
}

// ---- per-layer GEMM (standalone, layers 2/3) -------------------------------
__global__ void k_gemm_mfma(const ushort* __restrict__ hb, const ushort* __restrict__ Wp,
                            const float* __restrict__ avs, const float* __restrict__ avd,
                            ushort* __restrict__ gb, float* __restrict__ a_src,
                            float* __restrict__ a_dst, int N) {
    __shared__ ushort hs[64 * 136];
    int tid = threadIdx.x;
    int nb = blockIdx.x * 64;
#pragma unroll
    for (int it = 0; it < 4; ++it) {
        int fi = it * 256 + tid;
        int r = fi >> 4;
        int c8 = (fi & 15) * 8;
        int node = nb + r;
        uint4 v = make_uint4(0, 0, 0, 0);
        if (node < N) v = *(const uint4*)(hb + (size_t)node * H + c8);
        *(uint4*)(hs + r * 136 + c8) = v;
    }
    __syncthreads();
    const int l = tid & 63;
    const int w = tid >> 6;
    const int cl = l & 15;
    const int kg = l >> 4;
    const ushort* hrow = hs + (w * 16 + cl) * 136 + kg * 8;
    short8v a0 = *(const short8v*)(hrow + 0);
    short8v a1 = *(const short8v*)(hrow + 32);
    short8v a2 = *(const short8v*)(hrow + 64);
    short8v a3 = *(const short8v*)(hrow + 96);

    f32x4 acc[8];
#pragma unroll
    for (int nt = 0; nt < 8; ++nt) {
        const short8v* bp = (const short8v*)(Wp + ((size_t)(nt * 4) * 64 + l) * 8);
        f32x4 c = {0.f, 0.f, 0.f, 0.f};
        c = __builtin_amdgcn_mfma_f32_16x16x32_bf16(a0, bp[0], c, 0, 0, 0);
        c = __builtin_amdgcn_mfma_f32_16x16x32_bf16(a1, bp[64], c, 0, 0, 0);
        c = __builtin_amdgcn_mfma_f32_16x16x32_bf16(a2, bp[128], c, 0, 0, 0);
        c = __builtin_amdgcn_mfma_f32_16x16x32_bf16(a3, bp[192], c, 0, 0, 0);
        acc[nt] = c;
    }

    float ps0 = 0.f, ps1 = 0.f, ps2 = 0.f, ps3 = 0.f;
    float pd0 = 0.f, pd1 = 0.f, pd2 = 0.f, pd3 = 0.f;
#pragma unroll
    for (int nt = 0; nt < 8; ++nt) {
        float vs = avs[cl + 16 * nt];
        float vd = avd[cl + 16 * nt];
        ps0 = fmaf(acc[nt].x, vs, ps0); pd0 = fmaf(acc[nt].x, vd, pd0);
        ps1 = fmaf(acc[nt].y, vs, ps1); pd1 = fmaf(acc[nt].y, vd, pd1);
        ps2 = fmaf(acc[nt].z, vs, ps2); pd2 = fmaf(acc[nt].z, vd, pd2);
        ps3 = fmaf(acc[nt].w, vs, ps3); pd3 = fmaf(acc[nt].w, vd, pd3);
    }
#pragma unroll
    for (int m = 8; m >= 1; m >>= 1) {
        ps0 += __shfl_xor(ps0, m, 64); pd0 += __shfl_xor(pd0, m, 64);
        ps1 += __shfl_xor(ps1, m, 64); pd1 += __shfl_xor(pd1, m, 64);
        ps2 += __shfl_xor(ps2, m, 64); pd2 += __shfl_xor(pd2, m, 64);
        ps3 += __shfl_xor(ps3, m, 64); pd3 += __shfl_xor(pd3, m, 64);
    }
    int r0 = nb + w * 16 + kg * 4;
    if (cl == 0) {
        if (r0 + 0 < N) { a_src[r0 + 0] = ps0; a_dst[r0 + 0] = pd0; }
        if (r0 + 1 < N) { a_src[r0 + 1] = ps1; a_dst[r0 + 1] = pd1; }
        if (r0 + 2 < N) { a_src[r0 + 2] = ps2; a_dst[r0 + 2] = pd2; }
        if (r0 + 3 < N) { a_src[r0 + 3] = ps3; a_dst[r0 + 3] = pd3; }
    }
#pragma unroll
    for (int nt = 0; nt < 8; ++nt) {
        int col = nt * 16 + cl;
        if (r0 + 0 < N) gb[(size_t)(r0 + 0) * H + col] = f2bf(acc[nt].x);
        if (r0 + 1 < N) gb[(size_t)(r0 + 1) * H + col] = f2bf(acc[nt].y);
        if (r0 + 2 < N) gb[(size_t)(r0 + 2) * H + col] = f2bf(acc[nt].z);
        if (r0 + 3 < N) gb[(size_t)(r0 + 3) * H + col] = f2bf(acc[nt].w);
    }
}

// ---- aggregation: wave per node, online softmax, pipelined 16B gather ------
// (R8 body: VGPR 32, occupancy ~70%. MODE 0: relu+bf16 out; 1: +h0, fp32.)
template <int MODE>
__global__ void k_agg(const ushort* __restrict__ gb, const float* __restrict__ a_src,
                      const float* __restrict__ a_dst, const int* __restrict__ rowptr,
                      const uint* __restrict__ erecL, const float* __restrict__ park,
                      int layer, const float* __restrict__ bias,
                      const float* __restrict__ h0, float* __restrict__ outf,
                      ushort* __restrict__ outb, int N) {
    int wv = threadIdx.x >> 6;
    int lane = threadIdx.x & 63;
    int v = blockIdx.x * 4 + wv;
    if (v >= N) return;

    const int grp = lane >> 4;   // which of 4 edge-slots this lane serves
    const int sub = lane & 15;   // position within the 256B row
    const int ch8 = sub * 8;     // 8 bf16 channels per lane

    const float sa = park[layer * 3 + 2];
    const float adv = a_dst[v];
    float lself = a_src[v] + adv + sa;
    lself = (lself > 0.f) ? lself : 0.2f * lself;

    float m = lself;   // running max (self-loop included)
    float s = 1.f;     // running sum, w_self = exp(0) = 1
    float acc[8];
    {
        const uint4 q = *(const uint4*)(gb + (size_t)v * H + ch8);
        float sel = (grp == 0) ? 1.f : 0.f;  // self contribution counted once
        acc[0] = sel * __uint_as_float(q.x << 16);
        acc[1] = sel * __uint_as_float(q.x & 0xffff0000u);
        acc[2] = sel * __uint_as_float(q.y << 16);
        acc[3] = sel * __uint_as_float(q.y & 0xffff0000u);
        acc[4] = sel * __uint_as_float(q.z << 16);
        acc[5] = sel * __uint_as_float(q.z & 0xffff0000u);
        acc[6] = sel * __uint_as_float(q.w << 16);
        acc[7] = sel * __uint_as_float(q.w & 0xffff0000u);
    }

    const int rs = rowptr[v];
    const int re = rowptr[v + 1];
    for (int p0 = rs; p0 < re; p0 += 64) {
        int e = p0 + lane;
        bool val = e < re;
        uint rec = val ? erecL[e] : 0u;
        int sv = (int)(rec & 0xFFFFu);
        float lg;
        if (val) {
            float aef = __uint_as_float(rec & 0xffff0000u);
            lg = a_src[sv] + adv + aef;
            lg = (lg > 0.f) ? lg : 0.2f * lg;
        } else {
            lg = -INFINITY;
        }
        float cm = wred_max(lg);
        float nm = fmaxf(m, cm);
        float f = __expf(m - nm);
        float w = val ? __expf(lg - nm) : 0.f;
        float ws = wred_sum(w);
        s = s * f + ws;
#pragma unroll
        for (int k = 0; k < 8; ++k) acc[k] *= f;
        m = nm;

        int cnt = re - p0;
        if (cnt > 64) cnt = 64;
        const int cm1 = cnt - 1;
        const int iters = (cnt + 7) >> 3;  // 8 edges per super-iteration

        int jA = grp, jB = grp + 4;
        int jAc = (jA <= cm1) ? jA : cm1;
        int jBc = (jB <= cm1) ? jB : cm1;
        float wA = __shfl(w, jAc, 64); if (jA > cm1) wA = 0.f;
        float wB = __shfl(w, jBc, 64); if (jB > cm1) wB = 0.f;
        int sA = __shfl(sv, jAc, 64);
        int sB = __shfl(sv, jBc, 64);
        uint4 qA = *(const uint4*)(gb + (size_t)sA * H + ch8);
        uint4 qB = *(const uint4*)(gb + (size_t)sB * H + ch8);

        for (int i = 0; i < iters; ++i) {
            int jA1 = (i + 1) * 8 + grp, jB1 = jA1 + 4;
            int jA1c = (jA1 <= cm1) ? jA1 : cm1;
            int jB1c = (jB1 <= cm1) ? jB1 : cm1;
            float wA1 = __shfl(w, jA1c, 64); if (jA1 > cm1) wA1 = 0.f;
            float wB1 = __shfl(w, jB1c, 64); if (jB1 > cm1) wB1 = 0.f;
            int sA1 = __shfl(sv, jA1c, 64);
            int sB1 = __shfl(sv, jB1c, 64);
            uint4 qA1 = *(const uint4*)(gb + (size_t)sA1 * H + ch8);
            uint4 qB1 = *(const uint4*)(gb + (size_t)sB1 * H + ch8);

            acc[0] = fmaf(wA, __uint_as_float(qA.x << 16), acc[0]);
            acc[1] = fmaf(wA, __uint_as_float(qA.x & 0xffff0000u), acc[1]);
            acc[2] = fmaf(wA, __uint_as_float(qA.y << 16), acc[2]);
            acc[3] = fmaf(wA, __uint_as_float(qA.y & 0xffff0000u), acc[3]);
            acc[4] = fmaf(wA, __uint_as_float(qA.z << 16), acc[4]);
            acc[5] = fmaf(wA, __uint_as_float(qA.z & 0xffff0000u), acc[5]);
            acc[6] = fmaf(wA, __uint_as_float(qA.w << 16), acc[6]);
            acc[7] = fmaf(wA, __uint_as_float(qA.w & 0xffff0000u), acc[7]);
            acc[0] = fmaf(wB, __uint_as_float(qB.x << 16), acc[0]);
            acc[1] = fmaf(wB, __uint_as_float(qB.x & 0xffff0000u), acc[1]);
            acc[2] = fmaf(wB, __uint_as_float(qB.y << 16), acc[2]);
            acc[3] = fmaf(wB, __uint_as_float(qB.y & 0xffff0000u), acc[3]);
            acc[4] = fmaf(wB, __uint_as_float(qB.z << 16), acc[4]);
            acc[5] = fmaf(wB, __uint_as_float(qB.z & 0xffff0000u), acc[5]);
            acc[6] = fmaf(wB, __uint_as_float(qB.w << 16), acc[6]);
            acc[7] = fmaf(wB, __uint_as_float(qB.w & 0xffff0000u), acc[7]);

            wA = wA1; wB = wB1; qA = qA1; qB = qB1;
        }
    }

    // combine the 4 group-partials (lanes sub, sub+16, sub+32, sub+48)
#pragma unroll
    for (int k = 0; k < 8; ++k) {
        acc[k] += __shfl_xor(acc[k], 16, 64);
        acc[k] += __shfl_xor(acc[k], 32, 64);
    }

    if (grp == 0) {
        const float is = 1.f / s;
        const float4 b0 = *(const float4*)(bias + ch8);
        const float4 b1 = *(const float4*)(bias + ch8 + 4);
        float o[8];
        o[0] = acc[0] * is + b0.x; o[1] = acc[1] * is + b0.y;
        o[2] = acc[2] * is + b0.z; o[3] = acc[3] * is + b0.w;
        o[4] = acc[4] * is + b1.x; o[5] = acc[5] * is + b1.y;
        o[6] = acc[6] * is + b1.z; o[7] = acc[7] * is + b1.w;
        if (MODE == 0) {
#pragma unroll
            for (int k = 0; k < 8; ++k) o[k] = fmaxf(o[k], 0.f);
            uint4 ob;
            ob.x = (uint)f2bf(o[0]) | ((uint)f2bf(o[1]) << 16);
            ob.y = (uint)f2bf(o[2]) | ((uint)f2bf(o[3]) << 16);
            ob.z = (uint)f2bf(o[4]) | ((uint)f2bf(o[5]) << 16);
            ob.w = (uint)f2bf(o[6]) | ((uint)f2bf(o[7]) << 16);
            *(uint4*)(outb + (size_t)v * H + ch8) = ob;
        } else {
            const float4 ha = *(const float4*)(h0 + (size_t)v * H + ch8);
            const float4 hb4 = *(const float4*)(h0 + (size_t)v * H + ch8 + 4);
            o[0] += ha.x; o[1] += ha.y; o[2] += ha.z; o[3] += ha.w;
            o[4] += hb4.x; o[5] += hb4.y; o[6] += hb4.z; o[7] += hb4.w;
            *(float4*)(outf + (size_t)v * H + ch8) = make_float4(o[0], o[1], o[2], o[3]);
            *(float4*)(outf + (size_t)v * H + ch8 + 4) = make_float4(o[4], o[5], o[6], o[7]);
        }
    }
}

// ---------------------------------------------------------------------------

extern "C" void kernel_launch(void* const* d_in, const int* in_sizes, int n_in,
                              void* d_out, int out_size, void* d_ws, size_t ws_size,
                              hipStream_t stream) {
    const float* x    = (const float*)d_in[0];
    const int*   ei   = (const int*)d_in[1];
    const float* ea   = (const float*)d_in[2];
    const float* encW = (const float*)d_in[3];
    const float* encb = (const float*)d_in[4];
    const float* bng  = (const float*)d_in[5];
    const float* bnb  = (const float*)d_in[6];
    const float *W[3], *asrc[3], *adst[3], *We[3], *aev[3], *bias[3];
    for (int l = 0; l < 3; ++l) {
        W[l]    = (const float*)d_in[7 + l * 6 + 0];
        asrc[l] = (const float*)d_in[7 + l * 6 + 1];
        adst[l] = (const float*)d_in[7 + l * 6 + 2];
        We[l]   = (const float*)d_in[7 + l * 6 + 3];
        aev[l]  = (const float*)d_in[7 + l * 6 + 4];
        bias[l] = (const float*)d_in[7 + l * 6 + 5];
    }
    const int N = in_sizes[0] / NF;   // 50000 (< 65536: src packs in 16 bits)
    const int E = in_sizes[1] / 2;
    float* out = (float*)d_out;

    const int NBu  = (N + 255) >> 8;          // coarse buckets (196)
    const int nblk = (E + EPB - 1) / EPB;     // count/place blocks (391)
    const int GB8  = (N + 7) / 8;             // encoder blocks
    const int GBM  = (N + 63) / 64;           // gemm blocks
    const int AB   = (N + 3) / 4;             // agg blocks

    // workspace carve-up (256B aligned)
    char* wp = (char*)d_ws;
    auto alloc = [&](size_t bytes) -> char* {
        char* p = wp;
        wp += (bytes + 255) & ~(size_t)255;
        return p;
    };
    float*  h0       = (float*)alloc((size_t)N * H * 4);
    ushort* hb       = (ushort*)alloc((size_t)N * H * 2);
    ushort* gb       = (ushort*)alloc((size_t)N * H * 2);
    ushort* Wp       = (ushort*)alloc((size_t)3 * 16384 * 2);
    float*  a_src    = (float*)alloc((size_t)N * 4);
    float*  a_dst    = (float*)alloc((size_t)N * 4);
    int*    rowptr   = (int*)alloc((size_t)(N + 1) * 4);
    float*  park     = (float*)alloc(64);
    int*    bucketTotal = (int*)alloc(256 * 4);
    int*    bucketBase  = (int*)alloc(257 * 4);
    int*    blockBase   = (int*)alloc((size_t)NBu * nblk * 4);
    uint*   er0      = (uint*)alloc((size_t)E * 4);
    uint*   er1      = (uint*)alloc((size_t)E * 4);
    uint*   er2      = (uint*)alloc((size_t)E * 4);
    float2* pmean    = (float2*)alloc((size_t)nblk * 8);
    uint2*  temp     = (uint2*)alloc((size_t)E * 8);

    hipMemsetAsync(bucketTotal, 0, 256 * 4, stream);

    // A: count || encoder || wpack
    k_fusedA<<<nblk + GB8 + 3, 256, 0, stream>>>(
        ei, ea, E, nblk, NBu, bucketTotal, blockBase, pmean,
        x, encW, encb, bng, bnb, h0, hb, N, GB8,
        W[0], W[1], W[2], Wp);
    k_scan_park<<<1, 256, 0, stream>>>(bucketTotal, NBu, bucketBase, rowptr, N, E,
                                       pmean, nblk, 1.0f / (float)E,
                                       We[0], aev[0], We[1], aev[1], We[2], aev[2], park);
    // B: place || gemm layer 1
    k_fusedB<<<nblk + GBM, 256, 0, stream>>>(
        ei, ea, E, nblk, NBu, bucketBase, blockBase, temp,
        hb, Wp + 0 * 16384, asrc[0], adst[0], gb, a_src, a_dst, N);
    k_fine<<<NBu, 256, 0, stream>>>(temp, bucketBase, park, N, er0, er1, er2, rowptr);

    // layer 1 aggregate: gb -> hb
    k_agg<0><<<AB, 256, 0, stream>>>(gb, a_src, a_dst, rowptr, er0, park, 0,
                                     bias[0], nullptr, nullptr, hb, N);
    // layer 2
    k_gemm_mfma<<<GBM, 256, 0, stream>>>(hb, Wp + 1 * 16384, asrc[1], adst[1],
                                         gb, a_src, a_dst, N);
    k_agg<0><<<AB, 256, 0, stream>>>(gb, a_src, a_dst, rowptr, er1, park, 1,
                                     bias[1], nullptr, nullptr, hb, N);
    // layer 3: out = agg + h0 (fp32)
    k_gemm_mfma<<<GBM, 256, 0, stream>>>(hb, Wp + 2 * 16384, asrc[2], adst[2],
                                         gb, a_src, a_dst, N);
    k_agg<1><<<AB, 256, 0, stream>>>(gb, a_src, a_dst, rowptr, er2, park, 2,
                                     bias[2], h0, out, nullptr, N);
}